// Round 1
// baseline (446.893 us; speedup 1.0000x reference)
//
#include <hip/hip_runtime.h>

// LIF neuron scan: x [T=16, B=32, C=128, H=32, W=32] fp32 -> spikes same shape.
//   u1   = mem*0.5 + x*0.5 ; spk = (u1 > 1) ; mem' = spk ? 0 : u1
// Sequential only in T; all B*C*H*W positions independent.
//
// History:
//  R1: 1 column/thread, per-t round trip — latency-bound, 2.3 TB/s.
//  R3-R5: cross-iteration load hoist attempts — compiler sank loads (R3/R4) or
//      hand-asm broke waitcnt ordering (R5).
//  R6: 4 block-strided columns/thread, per-t batch of 4 loads — still one
//      vmcnt(0) round trip per T-iteration (16 exposed RTs/wave; stores also
//      count in vmcnt so each drain waits on the previous stores too).
//  R7 (this): transpose the per-thread work. One float4 column, ALL 16 time
//      steps loaded up front into v[16] (64 VGPRs, 16 loads in flight = 16 KB
//      per wave vs 4 KB), then the serial LIF chain runs in registers and
//      streams the 16 stores out. Latency paid once instead of 16 times.
//      An empty asm memory fence pins the load/compute phase boundary so the
//      scheduler can't sink loads to their uses (the R3/R4 failure mode);
//      waitcnt insertion stays entirely with the compiler (avoids R5's bug).
//      __launch_bounds__(256,2) budgets 128 VGPRs so all of v[] stays live.

constexpr int   T_STEPS     = 16;
constexpr float DECAY       = 0.5f;   // 1 - 1/tau, tau=2
constexpr float INPUT_SCALE = 0.5f;   // 1/tau
constexpr float THRESH      = 1.0f;

typedef float floatx4 __attribute__((ext_vector_type(4)));

__global__ __launch_bounds__(256, 2) void lif_scan_kernel(
    const float* __restrict__ x,
    float*       __restrict__ out,
    int n4)                           // float4s per time slice (1,048,576)
{
    const int idx = blockIdx.x * 256 + threadIdx.x;   // this thread's column

    const floatx4* __restrict__ xv  = reinterpret_cast<const floatx4*>(x);
    floatx4*       __restrict__ ov  = reinterpret_cast<floatx4*>(out);

    // ---- Phase 1: issue all T independent loads (16 KB in flight/wave).
    // Streaming data, touched exactly once -> nontemporal.
    floatx4 v[T_STEPS];
    #pragma unroll
    for (int t = 0; t < T_STEPS; ++t)
        v[t] = __builtin_nontemporal_load(&xv[(size_t)t * (size_t)n4 + (size_t)idx]);

    // Compile-time fence: loads above may not sink below, stores below may
    // not hoist above. No hand-written memory ops — compiler owns waitcnts.
    asm volatile("" ::: "memory");

    // ---- Phase 2: serial LIF chain in registers; stream each slice out.
    floatx4 mem = (floatx4)(0.f);
    #pragma unroll
    for (int t = 0; t < T_STEPS; ++t) {
        floatx4 s;
        #pragma unroll
        for (int k = 0; k < 4; ++k) {
            const float u = mem[k] * DECAY + v[t][k] * INPUT_SCALE;
            s[k]   = (u > THRESH) ? 1.0f : 0.0f;
            mem[k] = (u > THRESH) ? 0.0f : u;
        }
        __builtin_nontemporal_store(s, &ov[(size_t)t * (size_t)n4 + (size_t)idx]);
    }
}

extern "C" void kernel_launch(void* const* d_in, const int* in_sizes, int n_in,
                              void* d_out, int out_size, void* d_ws, size_t ws_size,
                              hipStream_t stream) {
    const float* x   = (const float*)d_in[0];
    float*       out = (float*)d_out;

    const int total   = in_sizes[0];          // T * B * C * H * W = 67,108,864
    const int n_per_t = total / T_STEPS;      // 4,194,304 floats per slice
    const int n4      = n_per_t / 4;          // 1,048,576 float4 columns

    const int threads = 256;
    const int blocks  = n4 / threads;         // 4096 blocks

    lif_scan_kernel<<<blocks, threads, 0, stream>>>(x, out, n4);
}

// Round 2
// 431.758 us; speedup vs baseline: 1.0351x; 1.0351x over previous
//
#include <hip/hip_runtime.h>

// LIF neuron scan: x [T=16, B=32, C=128, H=32, W=32] fp32 -> spikes same shape.
//   u1   = mem*0.5 + x*0.5 ; spk = (u1 > 1) ; mem' = spk ? 0 : u1
// Sequential only in T; all B*C*H*W positions independent.
//
// History:
//  R1: 1 column/thread, per-t round trip — latency-bound, 2.3 TB/s.
//  R3-R5: cross-iteration load hoist attempts — compiler sank loads (R3/R4) or
//      hand-asm broke waitcnt ordering (R5).
//  R6 (428-430us bench): 4 block-strided columns/thread, per-t batch of 4
//      loads. Remaining defect: program order loads(t)->compute->stores(t)
//      forces vmcnt(0) before each compute (loads(t) are the YOUNGEST
//      outstanding VMEM ops), so every iteration also waits for the previous
//      iteration's STORE ACKS. 16 serialized drains.
//  R7 (446.9us, REGRESSED): all-16-slices-in-registers. VGPR 48->~90 halved
//      occupancy, monolithic read-burst/write-burst per wave; latency was
//      never the binding constraint (Little's law: ~9-18KB/CU suffices).
//  R8 (this): R6's exact access pattern + ONE change: issue loads(t+1)
//      BEFORE stores(t). The wait for v(t) then has 8 younger ops outstanding
//      (stores(t-1) + loads(t+1)) -> compiler emits vmcnt(8), never blocking
//      on store acks, and each load batch gets a full iteration of slack.
//      Empty asm memory fence pins the order (prefetch can't sink below it,
//      stores can't hoist above it); waitcnts stay compiler-owned.

constexpr int   T_STEPS     = 16;
constexpr int   COLS        = 4;      // float4 columns per thread
constexpr float DECAY       = 0.5f;   // 1 - 1/tau, tau=2
constexpr float INPUT_SCALE = 0.5f;   // 1/tau
constexpr float THRESH      = 1.0f;

typedef float floatx4 __attribute__((ext_vector_type(4)));

__global__ __launch_bounds__(256) void lif_scan_kernel(
    const float* __restrict__ x,
    float*       __restrict__ out,
    int n_per_t)                      // elements per time slice (4,194,304)
{
    const int n4 = n_per_t >> 2;                       // float4s per slice
    const int f4_base = blockIdx.x * (256 * COLS) + threadIdx.x;

    const floatx4* __restrict__ xin  = reinterpret_cast<const floatx4*>(x);
    floatx4*       __restrict__ outv = reinterpret_cast<floatx4*>(out);

    floatx4 mem[COLS];
    #pragma unroll
    for (int c = 0; c < COLS; ++c) mem[c] = (floatx4)(0.f);

    // Prologue: issue loads for t=0.
    floatx4 v[COLS];
    #pragma unroll
    for (int c = 0; c < COLS; ++c)
        v[c] = xin[(size_t)f4_base + c * 256];

    #pragma unroll
    for (int t = 0; t < T_STEPS; ++t) {
        const size_t slice = (size_t)t * (size_t)n4 + (size_t)f4_base;

        // Prefetch next slice BEFORE this iteration's stores.
        floatx4 vn[COLS];
        if (t + 1 < T_STEPS) {
            const size_t slice1 = slice + (size_t)n4;
            #pragma unroll
            for (int c = 0; c < COLS; ++c)
                vn[c] = xin[slice1 + c * 256];
        }

        // Compile-time fence: prefetch loads above may not sink below this
        // point; stores below may not hoist above it. No hand-written memory
        // ops — the compiler owns all s_waitcnt insertion.
        asm volatile("" ::: "memory");

        #pragma unroll
        for (int c = 0; c < COLS; ++c) {
            floatx4 u, s;
            #pragma unroll
            for (int k = 0; k < 4; ++k) {
                u[k]      = mem[c][k] * DECAY + v[c][k] * INPUT_SCALE;
                s[k]      = (u[k] > THRESH) ? 1.0f : 0.0f;
                mem[c][k] = (u[k] > THRESH) ? 0.0f : u[k];
            }
            outv[slice + c * 256] = s;
        }

        if (t + 1 < T_STEPS) {
            #pragma unroll
            for (int c = 0; c < COLS; ++c) v[c] = vn[c];   // register rotate (free after unroll)
        }
    }
}

extern "C" void kernel_launch(void* const* d_in, const int* in_sizes, int n_in,
                              void* d_out, int out_size, void* d_ws, size_t ws_size,
                              hipStream_t stream) {
    const float* x   = (const float*)d_in[0];
    float*       out = (float*)d_out;

    const int total   = in_sizes[0];          // T * B * C * H * W
    const int n_per_t = total / T_STEPS;      // 4,194,304

    const int threads = 256;
    const int n4      = n_per_t / 4;          // 1,048,576 float4s per slice
    const int blocks  = n4 / (threads * COLS);  // 1024 blocks

    lif_scan_kernel<<<blocks, threads, 0, stream>>>(x, out, n_per_t);
}

// Round 3
// 428.298 us; speedup vs baseline: 1.0434x; 1.0081x over previous
//
#include <hip/hip_runtime.h>

// LIF neuron scan: x [T=16, B=32, C=128, H=32, W=32] fp32 -> spikes same shape.
//   u1   = mem*0.5 + x*0.5 ; spk = (u1 > 1) ; mem' = spk ? 0 : u1
// Sequential only in T; all B*C*H*W positions independent.
//
// History:
//  R1: 1 column/thread  — latency-bound: 2 KB moved per serialized round trip
//      (load + store-ack chained through vmcnt(0)); 2.3 TB/s, VALUBusy 4%.
//  R3/R4: register hoist (+sched_barrier) — compiler sank the loads, no change.
//  R5: inline-asm hoist — ALU uses hoisted above the waitcnt asm => WRONG DATA.
//  R6 (THIS, best: 428.3/429.7us): 4 independent block-strided columns per
//      thread. The 4 loads per iteration are consumed in-iteration, so the
//      compiler batches them: 4 KB in flight per wave per RT, 4x amortization.
//  R7 (446.9us, REGRESSED): all-16-slices-in-registers. VGPR ~48->~90 halved
//      occupancy; burst-read/burst-write removed TLP overlap. Latency was not
//      the binding constraint (32 waves/CU already cover it).
//  R8 (431.8us, NEUTRAL): R6 + 1-iteration prefetch to decouple store acks
//      (vmcnt(8) instead of vmcnt(0)). No change: with 32 waves/CU, per-wave
//      drains are hidden by the other 31 waves.
//  CONCLUSION: kernel is at the mixed-stream HBM ceiling (~537 MB mandatory
//      fp32 traffic at ~6 TB/s ≈ 85-100us). Three schedules within noise;
//      bytes irreducible (single pass, fp32 I/O fixed by problem).

constexpr int   T_STEPS     = 16;
constexpr int   COLS        = 4;      // float4 columns per thread
constexpr float DECAY       = 0.5f;   // 1 - 1/tau, tau=2
constexpr float INPUT_SCALE = 0.5f;   // 1/tau
constexpr float THRESH      = 1.0f;

typedef float floatx4 __attribute__((ext_vector_type(4)));

__global__ __launch_bounds__(256) void lif_scan_kernel(
    const float* __restrict__ x,
    float*       __restrict__ out,
    int n_per_t)                      // elements per time slice (4,194,304)
{
    const int n4 = n_per_t >> 2;                       // float4s per slice
    // Block-strided columns: lane-adjacent addresses within each load inst.
    const int f4_base = blockIdx.x * (256 * COLS) + threadIdx.x;

    const floatx4* __restrict__ xin  = reinterpret_cast<const floatx4*>(x);
    floatx4*       __restrict__ outv = reinterpret_cast<floatx4*>(out);

    floatx4 mem[COLS];
    #pragma unroll
    for (int c = 0; c < COLS; ++c) mem[c] = (floatx4)(0.f);

    #pragma unroll
    for (int t = 0; t < T_STEPS; ++t) {
        const size_t slice = (size_t)t * (size_t)n4 + (size_t)f4_base;

        // 4 independent coalesced loads, batched back-to-back by the
        // scheduler (all precede their uses within this basic block).
        floatx4 v[COLS];
        #pragma unroll
        for (int c = 0; c < COLS; ++c)
            v[c] = xin[slice + c * 256];

        #pragma unroll
        for (int c = 0; c < COLS; ++c) {
            floatx4 u, s;
            #pragma unroll
            for (int k = 0; k < 4; ++k) {
                u[k]      = mem[c][k] * DECAY + v[c][k] * INPUT_SCALE;
                s[k]      = (u[k] > THRESH) ? 1.0f : 0.0f;
                mem[c][k] = (u[k] > THRESH) ? 0.0f : u[k];
            }
            outv[slice + c * 256] = s;
        }
    }
}

extern "C" void kernel_launch(void* const* d_in, const int* in_sizes, int n_in,
                              void* d_out, int out_size, void* d_ws, size_t ws_size,
                              hipStream_t stream) {
    const float* x   = (const float*)d_in[0];
    float*       out = (float*)d_out;

    const int total   = in_sizes[0];          // T * B * C * H * W
    const int n_per_t = total / T_STEPS;      // 4,194,304

    const int threads = 256;
    const int n4      = n_per_t / 4;          // 1,048,576 float4s per slice
    const int blocks  = n4 / (threads * COLS);  // 1024 blocks

    lif_scan_kernel<<<blocks, threads, 0, stream>>>(x, out, n_per_t);
}